// Round 1
// baseline (4407.159 us; speedup 1.0000x reference)
//
#include <hip/hip_runtime.h>
#include <stdint.h>

#define LANE ((int)(threadIdx.x & 63))
#define WID  ((int)(threadIdx.x >> 6))

__device__ __forceinline__ float exact_d2(float ax, float ay, float az,
                                          float bx, float by, float bz) {
  float dx = ax - bx, dy = ay - by, dz = az - bz;
  return __fadd_rn(__fadd_rn(__fmul_rn(dx, dx), __fmul_rn(dy, dy)), __fmul_rn(dz, dz));
}

__device__ __forceinline__ uint64_t shfl_xor_u64(uint64_t v, int off) {
  uint32_t lo = (uint32_t)v, hi = (uint32_t)(v >> 32);
  lo = __shfl_xor(lo, off);
  hi = __shfl_xor(hi, off);
  return ((uint64_t)hi << 32) | lo;
}

// ---------------- FPS: one block per batch, exact argmax semantics ----------------
template <int NPTS, int NSAMP>
__global__ __launch_bounds__(256) void fps_kernel(
    const float* __restrict__ coords,  // [B][NPTS][3]
    int* __restrict__ out_idx,         // [B][NSAMP]
    float* __restrict__ out_pos)       // [B][NSAMP][3] or nullptr
{
  constexpr int PT = NPTS / 256;
  const int b = blockIdx.x;
  const float* pos = coords + (size_t)b * NPTS * 3;
  __shared__ float sx[NPTS], sy[NPTS], sz[NPTS];
  __shared__ float swv[4];
  __shared__ int swi[4];
  __shared__ int sfar;

  float px[PT], py[PT], pz[PT], dd[PT];
  const int i0 = (int)threadIdx.x * PT;
#pragma unroll
  for (int k = 0; k < PT; ++k) {
    int i = i0 + k;
    px[k] = pos[i * 3 + 0];
    py[k] = pos[i * 3 + 1];
    pz[k] = pos[i * 3 + 2];
    sx[i] = px[k]; sy[i] = py[k]; sz[i] = pz[k];
    dd[k] = __builtin_inff();
  }
  if (threadIdx.x == 0) {
    out_idx[(size_t)b * NSAMP] = 0;
    if (out_pos) {
      out_pos[(size_t)b * NSAMP * 3 + 0] = pos[0];
      out_pos[(size_t)b * NSAMP * 3 + 1] = pos[1];
      out_pos[(size_t)b * NSAMP * 3 + 2] = pos[2];
    }
  }
  int far = 0;
  __syncthreads();

  for (int s = 1; s < NSAMP; ++s) {
    float fx = sx[far], fy = sy[far], fz = sz[far];
    float lv = -__builtin_inff();
    int li = 0;
#pragma unroll
    for (int k = 0; k < PT; ++k) {
      float d = exact_d2(px[k], py[k], pz[k], fx, fy, fz);
      dd[k] = fminf(dd[k], d);
      bool gt = dd[k] > lv;  // strict >: keeps first index within thread
      lv = gt ? dd[k] : lv;
      li = gt ? (i0 + k) : li;
    }
#pragma unroll
    for (int off = 1; off < 64; off <<= 1) {
      float ov = __shfl_xor(lv, off);
      int oi = __shfl_xor(li, off);
      bool take = (ov > lv) || (ov == lv && oi < li);
      lv = take ? ov : lv;
      li = take ? oi : li;
    }
    if (LANE == 0) { swv[WID] = lv; swi[WID] = li; }
    __syncthreads();
    if (threadIdx.x == 0) {
      float bv = swv[0];
      int bi = swi[0];
      for (int w = 1; w < 4; ++w) {
        if (swv[w] > bv || (swv[w] == bv && swi[w] < bi)) { bv = swv[w]; bi = swi[w]; }
      }
      sfar = bi;
      out_idx[(size_t)b * NSAMP + s] = bi;
      if (out_pos) {
        out_pos[((size_t)b * NSAMP + s) * 3 + 0] = sx[bi];
        out_pos[((size_t)b * NSAMP + s) * 3 + 1] = sy[bi];
        out_pos[((size_t)b * NSAMP + s) * 3 + 2] = sz[bi];
      }
    }
    __syncthreads();
    far = sfar;
  }
}

// ------- u = x @ W1_feat + b1 precompute (layer-1 factored through the gather) -------
__global__ __launch_bounds__(256) void u1_kernel(const float* __restrict__ feats,  // [8*4096][6]
                                                 const float* __restrict__ w1,     // [9][64]
                                                 const float* __restrict__ b1,
                                                 float* __restrict__ u1)           // [8*4096][64]
{
  int tid = blockIdx.x * 256 + (int)threadIdx.x;  // 2,097,152 threads
  int f = tid & 63;
  int row = tid >> 6;
  const float* x = feats + (size_t)row * 6;
  float acc = b1[f];
#pragma unroll
  for (int k = 0; k < 6; ++k) acc = fmaf(x[k], w1[k * 64 + f], acc);
  u1[(size_t)row * 64 + f] = acc;
}

__global__ __launch_bounds__(128) void u2_kernel(const float* __restrict__ h1,  // [8][4096][64]
                                                 const int* __restrict__ i1,    // [8][2048]
                                                 const float* __restrict__ w1,  // [67][128]
                                                 const float* __restrict__ b1,
                                                 float* __restrict__ u2)        // [8*2048][128]
{
  int row = blockIdx.x;  // 16384
  int f = (int)threadIdx.x;
  int b = row >> 11;
  int src = i1[row];
  const float* x = h1 + ((size_t)b * 4096 + src) * 64;
  float acc = b1[f];
#pragma unroll
  for (int k = 0; k < 64; ++k) acc = fmaf(x[k], w1[k * 128 + f], acc);
  u2[(size_t)row * 128 + f] = acc;
}

__global__ __launch_bounds__(256) void transpose_kernel(const float* __restrict__ w2a,
                                                        const float* __restrict__ w2b,
                                                        float* __restrict__ w2ta,
                                                        float* __restrict__ w2tb) {
  int gtid = blockIdx.x * 256 + (int)threadIdx.x;
  int stride = gridDim.x * 256;
  for (int t = gtid; t < 64 * 64; t += stride) w2ta[(t & 63) * 64 + (t >> 6)] = w2a[t];
  for (int t = gtid; t < 128 * 128; t += stride) w2tb[(t & 127) * 128 + (t >> 7)] = w2b[t];
}

// ---------------- PointConv: 1 wave per query, 1 neighbor per lane ----------------
template <int NPTS, int H, int CAP>
__global__ __launch_bounds__(256) void conv_kernel(
    const float* __restrict__ pos,  // [B][NPTS][3]
    const float* __restrict__ u,    // [B][NPTS][H]   (b1 + x@W1_feat)
    const float* __restrict__ w1r,  // [3][H]         (rel rows of W1)
    const float* __restrict__ w2t,  // [H][H] transposed: w2t[g][f]
    const float* __restrict__ b2,   // [H]
    float r2,
    float* __restrict__ out)        // [B][NPTS][H]
{
  constexpr int SLOTS = CAP / 64;
  __shared__ uint64_t lists[4][CAP];
  uint64_t* list = lists[WID];
  const int qid = blockIdx.x * 4 + WID;
  const int b = qid / NPTS, qi = qid % NPTS;
  const float* bpos = pos + (size_t)b * NPTS * 3;
  const int lane = LANE;
  const float qx = bpos[qi * 3 + 0], qy = bpos[qi * 3 + 1], qz = bpos[qi * 3 + 2];

  // ---- scan: compact in-radius candidates (exact d2, strict < r2) ----
  unsigned cnt = 0;
  const uint64_t ltmask = (1ull << lane) - 1ull;
  for (int base = 0; base < NPTS; base += 64) {
    int j = base + lane;
    float pjx = bpos[j * 3], pjy = bpos[j * 3 + 1], pjz = bpos[j * 3 + 2];
    float d = exact_d2(pjx, pjy, pjz, qx, qy, qz);
    bool pred = d < r2;
    uint64_t mask = __ballot(pred);
    if (pred) {
      unsigned posn = cnt + (unsigned)__popcll(mask & ltmask);
      if (posn < CAP) list[posn] = ((uint64_t)__float_as_uint(d) << 32) | (unsigned)j;
    }
    cnt += (unsigned)__popcll(mask);
  }
  if (cnt > CAP) cnt = CAP;

  // ---- selection: if >64 in radius, take exact 64 smallest (d, j) ----
  int m;
  unsigned nbr = 0;
  if (cnt <= 64) {
    m = (int)cnt;
    if (lane < m) nbr = (unsigned)(list[lane] & 0xFFFFFFFFu);
  } else {
    m = 64;
    uint64_t e[SLOTS];
#pragma unroll
    for (int si = 0; si < SLOTS; ++si) {
      int p = lane + 64 * si;
      e[si] = (p < (int)cnt) ? list[p] : ~0ull;
    }
    uint64_t T = 0;
#pragma unroll 1
    for (int t = 0; t < 64; ++t) {
      uint64_t lm = ~0ull;
#pragma unroll
      for (int si = 0; si < SLOTS; ++si) {
        uint64_t v = (t == 0 || e[si] > T) ? e[si] : ~0ull;
        lm = (v < lm) ? v : lm;
      }
#pragma unroll
      for (int off = 1; off < 64; off <<= 1) {
        uint64_t o = shfl_xor_u64(lm, off);
        lm = (o < lm) ? o : lm;
      }
      T = lm;  // wave-uniform t-th smallest
      if (t == lane) nbr = (unsigned)(T & 0xFFFFFFFFu);
    }
  }

  // ---- MLP: lane computes full MLP for its neighbor; butterfly-max aggregation ----
  const bool valid = lane < m;
  const int j = valid ? (int)nbr : 0;
  const float rx = bpos[j * 3 + 0] - qx;
  const float ry = bpos[j * 3 + 1] - qy;
  const float rz = bpos[j * 3 + 2] - qz;

  float y1[H];
  const float* urow = u + ((size_t)b * NPTS + j) * H;
#pragma unroll
  for (int f = 0; f < H; f += 4) {
    float4 v = *reinterpret_cast<const float4*>(urow + f);
    y1[f] = v.x; y1[f + 1] = v.y; y1[f + 2] = v.z; y1[f + 3] = v.w;
  }
#pragma unroll
  for (int f = 0; f < H; ++f) {
    float t0 = fmaf(rx, w1r[f], y1[f]);
    t0 = fmaf(ry, w1r[H + f], t0);
    t0 = fmaf(rz, w1r[2 * H + f], t0);
    y1[f] = fmaxf(t0, 0.0f);
  }

  float hout0 = 0.0f, hout1 = 0.0f;
#pragma unroll 1
  for (int g = 0; g < H; ++g) {
    const float* wrow = w2t + (size_t)g * H;  // uniform -> SGPR loads
    float a0 = 0.0f, a1 = 0.0f, a2 = 0.0f, a3 = 0.0f;
#pragma unroll
    for (int f = 0; f < H; f += 4) {
      a0 = fmaf(y1[f], wrow[f], a0);
      a1 = fmaf(y1[f + 1], wrow[f + 1], a1);
      a2 = fmaf(y1[f + 2], wrow[f + 2], a2);
      a3 = fmaf(y1[f + 3], wrow[f + 3], a3);
    }
    float acc = b2[g] + ((a0 + a1) + (a2 + a3));
    acc = valid ? acc : -__builtin_inff();
#pragma unroll
    for (int off = 1; off < 64; off <<= 1) acc = fmaxf(acc, __shfl_xor(acc, off));
    if (g == lane) hout0 = acc;
    if (H == 128) {
      if (g == lane + 64) hout1 = acc;
    }
  }
  float* orow = out + (size_t)qid * H;
  orow[lane] = hout0;
  if (H == 128) orow[64 + lane] = hout1;
}

// ---------------- global max pool over i2 + final linear ----------------
__global__ __launch_bounds__(512) void pool_linear_kernel(
    const float* __restrict__ h2,  // [8][2048][128]
    const int* __restrict__ i2,    // [8][512]
    const float* __restrict__ wl,  // [128][128]
    const float* __restrict__ bl,  // [128]
    float* __restrict__ out)       // [8][128]
{
  int b = blockIdx.x;
  int c = (int)threadIdx.x >> 7;
  int f = (int)threadIdx.x & 127;
  __shared__ float part[4][128];
  __shared__ float feat[128];
  float mx = -__builtin_inff();
  const int* idx = i2 + b * 512;
  for (int s = c * 128; s < c * 128 + 128; ++s) {
    int j = idx[s];
    mx = fmaxf(mx, h2[((size_t)b * 2048 + j) * 128 + f]);
  }
  part[c][f] = mx;
  __syncthreads();
  if (c == 0) feat[f] = fmaxf(fmaxf(part[0][f], part[1][f]), fmaxf(part[2][f], part[3][f]));
  __syncthreads();
  if (c == 0) {
    float acc = bl[f];
#pragma unroll
    for (int k = 0; k < 128; ++k) acc = fmaf(feat[k], wl[k * 128 + f], acc);
    out[b * 128 + f] = acc;
  }
}

extern "C" void kernel_launch(void* const* d_in, const int* in_sizes, int n_in,
                              void* d_out, int out_size, void* d_ws, size_t ws_size,
                              hipStream_t stream) {
  const float* feats = (const float*)d_in[0];   // [8,4096,6]
  const float* coords = (const float*)d_in[1];  // [8,4096,3]
  const float* W1a = (const float*)d_in[2];     // [9,64]
  const float* b1a = (const float*)d_in[3];
  const float* W2a = (const float*)d_in[4];     // [64,64]
  const float* b2a = (const float*)d_in[5];
  const float* W1b = (const float*)d_in[6];     // [67,128]
  const float* b1b = (const float*)d_in[7];
  const float* W2b = (const float*)d_in[8];     // [128,128]
  const float* b2b = (const float*)d_in[9];
  const float* Wl = (const float*)d_in[10];     // [128,128]
  const float* bl = (const float*)d_in[11];

  float* ws = (float*)d_ws;
  float* W2TA = ws;                    // 4096
  float* W2TB = W2TA + 4096;           // 16384
  float* U1 = W2TB + 16384;            // 8*4096*64   = 2097152
  float* H1 = U1 + 2097152;            // 8*4096*64
  float* U2 = H1 + 2097152;            // 8*2048*128  = 2097152
  float* H2 = U2 + 2097152;            // 8*2048*128
  float* P1 = H2 + 2097152;            // 8*2048*3    = 49152
  int* I1 = (int*)(P1 + 49152);        // 8*2048
  int* I2 = I1 + 16384;                // 8*512

  transpose_kernel<<<80, 256, 0, stream>>>(W2a, W2b, W2TA, W2TB);
  u1_kernel<<<8192, 256, 0, stream>>>(feats, W1a, b1a, U1);
  fps_kernel<4096, 2048><<<8, 256, 0, stream>>>(coords, I1, P1);
  conv_kernel<4096, 64, 512><<<8192, 256, 0, stream>>>(coords, U1, W1a + 6 * 64, W2TA, b2a,
                                                       0.04f, H1);
  u2_kernel<<<16384, 128, 0, stream>>>(H1, I1, W1b, b1b, U2);
  fps_kernel<2048, 512><<<8, 256, 0, stream>>>(P1, I2, nullptr);
  conv_kernel<2048, 128, 1024><<<4096, 256, 0, stream>>>(P1, U2, W1b + 64 * 128, W2TB, b2b,
                                                         0.16f, H2);
  pool_linear_kernel<<<8, 512, 0, stream>>>(H2, I2, Wl, bl, (float*)d_out);
}